// Round 1
// baseline (98.793 us; speedup 1.0000x reference)
//
#include <hip/hip_runtime.h>

#define FIXED_FRAMES 30
#define N_LM 543
#define N_SEL 107

__constant__ int c_sel[N_SEL] = {
    // LIPS (40)
    61, 185, 40, 39, 37, 0, 267, 269, 270, 409, 291,
    146, 91, 181, 84, 17, 314, 405, 321, 375,
    78, 191, 80, 81, 82, 13, 312, 311, 310, 415,
    95, 88, 178, 87, 14, 317, 402, 318, 324, 308,
    // LEFT_HAND (21): 468..488
    468, 469, 470, 471, 472, 473, 474, 475, 476, 477, 478,
    479, 480, 481, 482, 483, 484, 485, 486, 487, 488,
    // UPPER_BODY (25): 489..513
    489, 490, 491, 492, 493, 494, 495, 496, 497, 498, 499,
    500, 501, 502, 503, 504, 505, 506, 507, 508, 509, 510,
    511, 512, 513,
    // RIGHT_HAND (21): 522..542
    522, 523, 524, 525, 526, 527, 528, 529, 530, 531, 532,
    533, 534, 535, 536, 537, 538, 539, 540, 541, 542
};

// ws layout: [0]=sum (double), [1]=sumsq (double), [2]=count (unsigned long long)
__global__ void fp_init_ws(double* ws) {
    ws[0] = 0.0;
    ws[1] = 0.0;
    ((unsigned long long*)ws)[2] = 0ull;
}

__global__ void fp_reduce(const float4* __restrict__ x, int n4, double* __restrict__ ws) {
    double s = 0.0, s2 = 0.0;
    unsigned int c = 0;

    int idx = blockIdx.x * blockDim.x + threadIdx.x;
    int stride = gridDim.x * blockDim.x;
    for (int i = idx; i < n4; i += stride) {
        float4 v = x[i];
        float vals[4] = {v.x, v.y, v.z, v.w};
#pragma unroll
        for (int k = 0; k < 4; ++k) {
            float f = vals[k];
            if (f == f) {  // !isnan
                double d = (double)f;
                s += d;
                s2 += d * d;
                ++c;
            }
        }
    }

    // wave (64-lane) reduction
#pragma unroll
    for (int off = 32; off > 0; off >>= 1) {
        s  += __shfl_down(s, off, 64);
        s2 += __shfl_down(s2, off, 64);
        c  += __shfl_down(c, off, 64);
    }

    __shared__ double ls[4], ls2[4];
    __shared__ unsigned int lc[4];
    int lane = threadIdx.x & 63;
    int wave = threadIdx.x >> 6;
    if (lane == 0) { ls[wave] = s; ls2[wave] = s2; lc[wave] = c; }
    __syncthreads();
    if (threadIdx.x == 0) {
        double bs = 0.0, bs2 = 0.0;
        unsigned long long bc = 0;
        int nw = (blockDim.x + 63) >> 6;
        for (int w = 0; w < nw; ++w) { bs += ls[w]; bs2 += ls2[w]; bc += lc[w]; }
        atomicAdd(&ws[0], bs);
        atomicAdd(&ws[1], bs2);
        atomicAdd((unsigned long long*)ws + 2, bc);
    }
}

__global__ void fp_gather(const float* __restrict__ x, const double* __restrict__ ws,
                          float* __restrict__ out, int T) {
    int t = blockIdx.x * blockDim.x + threadIdx.x;
    const int total = FIXED_FRAMES * N_SEL * 3;
    if (t >= total) return;

    double S1 = ws[0];
    double S2 = ws[1];
    double dc = (double)(((const unsigned long long*)ws)[2]);

    double mean = S1 / dc;
    double m2 = (S1 - dc * mean) / dc;  // tiny fp residual, matches ref structure
    double mu = mean + m2;              // var is about (x - mean - m2)
    double var = (S2 - 2.0 * mu * S1 + dc * mu * mu) / (dc - 1.0);
    double inv_std = 1.0 / sqrt(var);

    int f = t / (N_SEL * 3);
    int r = t - f * (N_SEL * 3);
    int l = r / 3;
    int ch = r - l * 3;

    // nearest-exact resample index, replicated in float32 like the jax/f32 ref
    float scale = (float)T / 30.0f;
    int fi = (int)floorf(((float)f + 0.5f) * scale);
    if (fi > T - 1) fi = T - 1;
    if (fi < 0) fi = 0;

    float v = x[(size_t)fi * (N_LM * 3) + (size_t)c_sel[l] * 3 + ch];
    // y = (x - mean)/std  (NOT x - mu), NaN -> 0
    out[t] = (v == v) ? (float)(((double)v - mean) * inv_std) : 0.0f;
}

extern "C" void kernel_launch(void* const* d_in, const int* in_sizes, int n_in,
                              void* d_out, int out_size, void* d_ws, size_t ws_size,
                              hipStream_t stream) {
    const float* x = (const float*)d_in[0];
    float* out = (float*)d_out;
    double* ws = (double*)d_ws;

    int n = in_sizes[0];             // 16384*543*3 = 26,689,536 (divisible by 4)
    int n4 = n / 4;
    int T = n / (N_LM * 3);

    fp_init_ws<<<1, 1, 0, stream>>>(ws);

    int threads = 256;
    int blocks = 2048;               // ~13 float4 per thread grid-stride
    fp_reduce<<<blocks, threads, 0, stream>>>((const float4*)x, n4, ws);

    const int total = FIXED_FRAMES * N_SEL * 3;  // 9630
    fp_gather<<<(total + 255) / 256, 256, 0, stream>>>(x, ws, out, T);
}

// Round 2
// 29.409 us; speedup vs baseline: 3.3593x; 3.3593x over previous
//
#include <hip/hip_runtime.h>

#define FIXED_FRAMES 30
#define N_LM 543
#define N_SEL 107
#define NBLK 2048
#define NTHR 256

__constant__ int c_sel[N_SEL] = {
    // LIPS (40)
    61, 185, 40, 39, 37, 0, 267, 269, 270, 409, 291,
    146, 91, 181, 84, 17, 314, 405, 321, 375,
    78, 191, 80, 81, 82, 13, 312, 311, 310, 415,
    95, 88, 178, 87, 14, 317, 402, 318, 324, 308,
    // LEFT_HAND (21): 468..488
    468, 469, 470, 471, 472, 473, 474, 475, 476, 477, 478,
    479, 480, 481, 482, 483, 484, 485, 486, 487, 488,
    // UPPER_BODY (25): 489..513
    489, 490, 491, 492, 493, 494, 495, 496, 497, 498, 499,
    500, 501, 502, 503, 504, 505, 506, 507, 508, 509, 510,
    511, 512, 513,
    // RIGHT_HAND (21): 522..542
    522, 523, 524, 525, 526, 527, 528, 529, 530, 531, 532,
    533, 534, 535, 536, 537, 538, 539, 540, 541, 542
};

// ws layout (doubles):
//   [0      .. NBLK)    per-block sum
//   [NBLK   .. 2*NBLK)  per-block sumsq
//   [2*NBLK .. 3*NBLK)  per-block count (as double)
//   [3*NBLK]            mean
//   [3*NBLK+1]          inv_std

__device__ __forceinline__ void acc4(float4 v, double& s, double& s2, unsigned& c) {
    float vals[4] = {v.x, v.y, v.z, v.w};
#pragma unroll
    for (int k = 0; k < 4; ++k) {
        float f = vals[k];
        bool ok = (f == f);
        float fz = ok ? f : 0.0f;   // branchless cndmask
        double d = (double)fz;
        s += d;
        s2 += d * d;
        c += ok ? 1u : 0u;
    }
}

__global__ __launch_bounds__(NTHR) void fp_reduce(const float4* __restrict__ x, int n4,
                                                  double* __restrict__ ws) {
    double s = 0.0, s2 = 0.0;
    unsigned int c = 0;

    int idx = blockIdx.x * NTHR + threadIdx.x;
    const int stride = NBLK * NTHR;

    int i = idx;
    // 2-way unrolled grid-stride: two independent loads in flight per iter
    for (; i + stride < n4; i += 2 * stride) {
        float4 v0 = x[i];
        float4 v1 = x[i + stride];
        acc4(v0, s, s2, c);
        acc4(v1, s, s2, c);
    }
    if (i < n4) acc4(x[i], s, s2, c);

    // wave (64-lane) butterfly-free down-reduce
#pragma unroll
    for (int off = 32; off > 0; off >>= 1) {
        s  += __shfl_down(s, off, 64);
        s2 += __shfl_down(s2, off, 64);
        c  += __shfl_down(c, off, 64);
    }

    __shared__ double ls[4], ls2[4];
    __shared__ unsigned int lc[4];
    int lane = threadIdx.x & 63;
    int wave = threadIdx.x >> 6;
    if (lane == 0) { ls[wave] = s; ls2[wave] = s2; lc[wave] = c; }
    __syncthreads();
    if (threadIdx.x == 0) {
        double bs = 0.0, bs2 = 0.0;
        unsigned long long bc = 0;
#pragma unroll
        for (int w = 0; w < 4; ++w) { bs += ls[w]; bs2 += ls2[w]; bc += lc[w]; }
        ws[blockIdx.x]            = bs;
        ws[NBLK + blockIdx.x]     = bs2;
        ws[2 * NBLK + blockIdx.x] = (double)bc;
    }
}

__global__ __launch_bounds__(NTHR) void fp_final(double* __restrict__ ws) {
    double s = 0.0, s2 = 0.0, c = 0.0;
    for (int i = threadIdx.x; i < NBLK; i += NTHR) {
        s  += ws[i];
        s2 += ws[NBLK + i];
        c  += ws[2 * NBLK + i];
    }
#pragma unroll
    for (int off = 32; off > 0; off >>= 1) {
        s  += __shfl_down(s, off, 64);
        s2 += __shfl_down(s2, off, 64);
        c  += __shfl_down(c, off, 64);
    }
    __shared__ double ls[4], ls2[4], lc[4];
    int lane = threadIdx.x & 63;
    int wave = threadIdx.x >> 6;
    if (lane == 0) { ls[wave] = s; ls2[wave] = s2; lc[wave] = c; }
    __syncthreads();
    if (threadIdx.x == 0) {
        double S1 = 0.0, S2 = 0.0, dc = 0.0;
#pragma unroll
        for (int w = 0; w < 4; ++w) { S1 += ls[w]; S2 += ls2[w]; dc += lc[w]; }

        double mean = S1 / dc;
        double m2 = (S1 - dc * mean) / dc;   // fp residual, mirrors ref structure
        double mu = mean + m2;               // var is about (x - mean - m2)
        double var = (S2 - 2.0 * mu * S1 + dc * mu * mu) / (dc - 1.0);
        double inv_std = 1.0 / sqrt(var);

        ws[3 * NBLK]     = mean;
        ws[3 * NBLK + 1] = inv_std;
    }
}

__global__ void fp_gather(const float* __restrict__ x, const double* __restrict__ ws,
                          float* __restrict__ out, int T) {
    int t = blockIdx.x * blockDim.x + threadIdx.x;
    const int total = FIXED_FRAMES * N_SEL * 3;
    if (t >= total) return;

    double mean = ws[3 * NBLK];
    double inv_std = ws[3 * NBLK + 1];

    int f = t / (N_SEL * 3);
    int r = t - f * (N_SEL * 3);
    int l = r / 3;
    int ch = r - l * 3;

    // nearest-exact resample index, replicated in float32 like the jax/f32 ref
    float scale = (float)T / 30.0f;
    int fi = (int)floorf(((float)f + 0.5f) * scale);
    if (fi > T - 1) fi = T - 1;
    if (fi < 0) fi = 0;

    float v = x[(size_t)fi * (N_LM * 3) + (size_t)c_sel[l] * 3 + ch];
    out[t] = (v == v) ? (float)(((double)v - mean) * inv_std) : 0.0f;
}

extern "C" void kernel_launch(void* const* d_in, const int* in_sizes, int n_in,
                              void* d_out, int out_size, void* d_ws, size_t ws_size,
                              hipStream_t stream) {
    const float* x = (const float*)d_in[0];
    float* out = (float*)d_out;
    double* ws = (double*)d_ws;

    int n = in_sizes[0];             // 16384*543*3 = 26,689,536 (divisible by 4)
    int n4 = n / 4;
    int T = n / (N_LM * 3);

    fp_reduce<<<NBLK, NTHR, 0, stream>>>((const float4*)x, n4, ws);
    fp_final<<<1, NTHR, 0, stream>>>(ws);

    const int total = FIXED_FRAMES * N_SEL * 3;  // 9630
    fp_gather<<<(total + 255) / 256, 256, 0, stream>>>(x, ws, out, T);
}

// Round 3
// 28.168 us; speedup vs baseline: 3.5073x; 1.0441x over previous
//
#include <hip/hip_runtime.h>

#define FIXED_FRAMES 30
#define N_LM 543
#define N_SEL 107
#define NBLK 2048
#define NTHR 256

__constant__ int c_sel[N_SEL] = {
    // LIPS (40)
    61, 185, 40, 39, 37, 0, 267, 269, 270, 409, 291,
    146, 91, 181, 84, 17, 314, 405, 321, 375,
    78, 191, 80, 81, 82, 13, 312, 311, 310, 415,
    95, 88, 178, 87, 14, 317, 402, 318, 324, 308,
    // LEFT_HAND (21): 468..488
    468, 469, 470, 471, 472, 473, 474, 475, 476, 477, 478,
    479, 480, 481, 482, 483, 484, 485, 486, 487, 488,
    // UPPER_BODY (25): 489..513
    489, 490, 491, 492, 493, 494, 495, 496, 497, 498, 499,
    500, 501, 502, 503, 504, 505, 506, 507, 508, 509, 510,
    511, 512, 513,
    // RIGHT_HAND (21): 522..542
    522, 523, 524, 525, 526, 527, 528, 529, 530, 531, 532,
    533, 534, 535, 536, 537, 538, 539, 540, 541, 542
};

// ws layout (doubles):
//   [0      .. NBLK)    per-block sum
//   [NBLK   .. 2*NBLK)  per-block sumsq
//   [2*NBLK .. 3*NBLK)  per-block count (as double)

// Per-thread f32 accumulation (each thread sees only ~51 elements; error
// ~1e-5 absolute vs 7.4e-2 threshold), f64 from the cross-lane reduce on.
__device__ __forceinline__ void acc4f(float4 v, float& s, float& s2, unsigned& c) {
    float vals[4] = {v.x, v.y, v.z, v.w};
#pragma unroll
    for (int k = 0; k < 4; ++k) {
        float f = vals[k];
        bool ok = (f == f);
        float fz = ok ? f : 0.0f;       // branchless cndmask
        s  += fz;
        s2 = fmaf(fz, fz, s2);
        c  += ok ? 1u : 0u;
    }
}

__global__ __launch_bounds__(NTHR) void fp_reduce(const float4* __restrict__ x, int n4,
                                                  double* __restrict__ ws) {
    float s = 0.0f, s2 = 0.0f;
    unsigned int c = 0;

    int idx = blockIdx.x * NTHR + threadIdx.x;
    const int stride = NBLK * NTHR;

    int i = idx;
    // 4-way unrolled grid-stride: 4 independent 16B loads in flight per iter
    for (; i + 3 * stride < n4; i += 4 * stride) {
        float4 v0 = x[i];
        float4 v1 = x[i + stride];
        float4 v2 = x[i + 2 * stride];
        float4 v3 = x[i + 3 * stride];
        acc4f(v0, s, s2, c);
        acc4f(v1, s, s2, c);
        acc4f(v2, s, s2, c);
        acc4f(v3, s, s2, c);
    }
    for (; i < n4; i += stride) acc4f(x[i], s, s2, c);

    // cross-lane in f64
    double sd = (double)s, s2d = (double)s2;
#pragma unroll
    for (int off = 32; off > 0; off >>= 1) {
        sd  += __shfl_down(sd, off, 64);
        s2d += __shfl_down(s2d, off, 64);
        c   += __shfl_down(c, off, 64);
    }

    __shared__ double ls[4], ls2[4];
    __shared__ unsigned int lc[4];
    int lane = threadIdx.x & 63;
    int wave = threadIdx.x >> 6;
    if (lane == 0) { ls[wave] = sd; ls2[wave] = s2d; lc[wave] = c; }
    __syncthreads();
    if (threadIdx.x == 0) {
        double bs = 0.0, bs2 = 0.0;
        unsigned long long bc = 0;
#pragma unroll
        for (int w = 0; w < 4; ++w) { bs += ls[w]; bs2 += ls2[w]; bc += lc[w]; }
        ws[blockIdx.x]            = bs;
        ws[NBLK + blockIdx.x]     = bs2;
        ws[2 * NBLK + blockIdx.x] = (double)bc;
    }
}

// Fused final-reduce + gather: every block redundantly folds the 2048
// partials (48 KB, L2-resident, ~256 reads/thread-block) then gathers.
__global__ __launch_bounds__(NTHR) void fp_gather(const float* __restrict__ x,
                                                  const double* __restrict__ ws,
                                                  float* __restrict__ out, int T) {
    double s = 0.0, s2 = 0.0, c = 0.0;
    for (int i = threadIdx.x; i < NBLK; i += NTHR) {
        s  += ws[i];
        s2 += ws[NBLK + i];
        c  += ws[2 * NBLK + i];
    }
#pragma unroll
    for (int off = 32; off > 0; off >>= 1) {
        s  += __shfl_down(s, off, 64);
        s2 += __shfl_down(s2, off, 64);
        c  += __shfl_down(c, off, 64);
    }
    __shared__ double ls[4], ls2[4], lc[4];
    __shared__ double sm_mean, sm_inv_std;
    int lane = threadIdx.x & 63;
    int wave = threadIdx.x >> 6;
    if (lane == 0) { ls[wave] = s; ls2[wave] = s2; lc[wave] = c; }
    __syncthreads();
    if (threadIdx.x == 0) {
        double S1 = 0.0, S2 = 0.0, dc = 0.0;
#pragma unroll
        for (int w = 0; w < 4; ++w) { S1 += ls[w]; S2 += ls2[w]; dc += lc[w]; }

        double mean = S1 / dc;
        double m2 = (S1 - dc * mean) / dc;   // fp residual, mirrors ref structure
        double mu = mean + m2;               // var is about (x - mean - m2)
        double var = (S2 - 2.0 * mu * S1 + dc * mu * mu) / (dc - 1.0);
        sm_mean = mean;
        sm_inv_std = 1.0 / sqrt(var);
    }
    __syncthreads();

    int t = blockIdx.x * NTHR + threadIdx.x;
    const int total = FIXED_FRAMES * N_SEL * 3;
    if (t >= total) return;

    double mean = sm_mean;
    double inv_std = sm_inv_std;

    int f = t / (N_SEL * 3);
    int r = t - f * (N_SEL * 3);
    int l = r / 3;
    int ch = r - l * 3;

    // nearest-exact resample index, replicated in float32 like the jax/f32 ref
    float scale = (float)T / 30.0f;
    int fi = (int)floorf(((float)f + 0.5f) * scale);
    if (fi > T - 1) fi = T - 1;
    if (fi < 0) fi = 0;

    float v = x[(size_t)fi * (N_LM * 3) + (size_t)c_sel[l] * 3 + ch];
    out[t] = (v == v) ? (float)(((double)v - mean) * inv_std) : 0.0f;
}

extern "C" void kernel_launch(void* const* d_in, const int* in_sizes, int n_in,
                              void* d_out, int out_size, void* d_ws, size_t ws_size,
                              hipStream_t stream) {
    const float* x = (const float*)d_in[0];
    float* out = (float*)d_out;
    double* ws = (double*)d_ws;

    int n = in_sizes[0];             // 16384*543*3 = 26,689,536 (divisible by 4)
    int n4 = n / 4;
    int T = n / (N_LM * 3);

    fp_reduce<<<NBLK, NTHR, 0, stream>>>((const float4*)x, n4, ws);

    const int total = FIXED_FRAMES * N_SEL * 3;  // 9630
    fp_gather<<<(total + NTHR - 1) / NTHR, NTHR, 0, stream>>>(x, ws, out, T);
}

// Round 5
// 25.972 us; speedup vs baseline: 3.8038x; 1.0845x over previous
//
#include <hip/hip_runtime.h>

#define FIXED_FRAMES 30
#define N_LM 543
#define N_SEL 107
#define NBLK 2048
#define NTHR 256

typedef float f32x4 __attribute__((ext_vector_type(4)));

__constant__ int c_sel[N_SEL] = {
    // LIPS (40)
    61, 185, 40, 39, 37, 0, 267, 269, 270, 409, 291,
    146, 91, 181, 84, 17, 314, 405, 321, 375,
    78, 191, 80, 81, 82, 13, 312, 311, 310, 415,
    95, 88, 178, 87, 14, 317, 402, 318, 324, 308,
    // LEFT_HAND (21): 468..488
    468, 469, 470, 471, 472, 473, 474, 475, 476, 477, 478,
    479, 480, 481, 482, 483, 484, 485, 486, 487, 488,
    // UPPER_BODY (25): 489..513
    489, 490, 491, 492, 493, 494, 495, 496, 497, 498, 499,
    500, 501, 502, 503, 504, 505, 506, 507, 508, 509, 510,
    511, 512, 513,
    // RIGHT_HAND (21): 522..542
    522, 523, 524, 525, 526, 527, 528, 529, 530, 531, 532,
    533, 534, 535, 536, 537, 538, 539, 540, 541, 542
};

// ws layout (doubles):
//   [0      .. NBLK)    per-block sum
//   [NBLK   .. 2*NBLK)  per-block sumsq
//   [2*NBLK .. 3*NBLK)  per-block count (as double)

// Lane-split f32 accumulation into a f32x4 bank: 4 independent partial
// sums -> short dep chains, packed f32 math. Error ~1e-5 abs vs 7.4e-2.
__device__ __forceinline__ void acc4v(f32x4 v, f32x4& s, f32x4& s2, unsigned& c) {
    bool ok0 = (v.x == v.x), ok1 = (v.y == v.y), ok2 = (v.z == v.z), ok3 = (v.w == v.w);
    float z0 = ok0 ? v.x : 0.0f;
    float z1 = ok1 ? v.y : 0.0f;
    float z2 = ok2 ? v.z : 0.0f;
    float z3 = ok3 ? v.w : 0.0f;
    s.x += z0; s.y += z1; s.z += z2; s.w += z3;
    s2.x = fmaf(z0, z0, s2.x);
    s2.y = fmaf(z1, z1, s2.y);
    s2.z = fmaf(z2, z2, s2.z);
    s2.w = fmaf(z3, z3, s2.w);
    c += (unsigned)ok0 + (unsigned)ok1 + (unsigned)ok2 + (unsigned)ok3;
}

__device__ __forceinline__ f32x4 ntload(const f32x4* p) {
    return __builtin_nontemporal_load(p);
}

__global__ __launch_bounds__(NTHR) void fp_reduce(const f32x4* __restrict__ x, int n4,
                                                  double* __restrict__ ws) {
    f32x4 sA = {0, 0, 0, 0}, s2A = {0, 0, 0, 0};
    f32x4 sB = {0, 0, 0, 0}, s2B = {0, 0, 0, 0};
    unsigned int c = 0;

    int idx = blockIdx.x * NTHR + threadIdx.x;
    const int stride = NBLK * NTHR;

    int i = idx;
    // loads/thread = 12 or 13 (n4/stride = 12.727): 8-in-flight + 4-in-flight + tail
    if (i + 7 * stride < n4) {
        f32x4 v0 = ntload(&x[i]);
        f32x4 v1 = ntload(&x[i + stride]);
        f32x4 v2 = ntload(&x[i + 2 * stride]);
        f32x4 v3 = ntload(&x[i + 3 * stride]);
        f32x4 v4 = ntload(&x[i + 4 * stride]);
        f32x4 v5 = ntload(&x[i + 5 * stride]);
        f32x4 v6 = ntload(&x[i + 6 * stride]);
        f32x4 v7 = ntload(&x[i + 7 * stride]);
        acc4v(v0, sA, s2A, c); acc4v(v1, sB, s2B, c);
        acc4v(v2, sA, s2A, c); acc4v(v3, sB, s2B, c);
        acc4v(v4, sA, s2A, c); acc4v(v5, sB, s2B, c);
        acc4v(v6, sA, s2A, c); acc4v(v7, sB, s2B, c);
        i += 8 * stride;
    }
    if (i + 3 * stride < n4) {
        f32x4 v0 = ntload(&x[i]);
        f32x4 v1 = ntload(&x[i + stride]);
        f32x4 v2 = ntload(&x[i + 2 * stride]);
        f32x4 v3 = ntload(&x[i + 3 * stride]);
        acc4v(v0, sA, s2A, c); acc4v(v1, sB, s2B, c);
        acc4v(v2, sA, s2A, c); acc4v(v3, sB, s2B, c);
        i += 4 * stride;
    }
    for (; i < n4; i += stride) {
        acc4v(ntload(&x[i]), sA, s2A, c);
    }

    // fold lane banks in f64, then cross-lane in f64
    double sd = ((double)sA.x + (double)sA.y) + ((double)sA.z + (double)sA.w)
              + ((double)sB.x + (double)sB.y) + ((double)sB.z + (double)sB.w);
    double s2d = ((double)s2A.x + (double)s2A.y) + ((double)s2A.z + (double)s2A.w)
               + ((double)s2B.x + (double)s2B.y) + ((double)s2B.z + (double)s2B.w);
#pragma unroll
    for (int off = 32; off > 0; off >>= 1) {
        sd  += __shfl_down(sd, off, 64);
        s2d += __shfl_down(s2d, off, 64);
        c   += __shfl_down(c, off, 64);
    }

    __shared__ double ls[4], ls2[4];
    __shared__ unsigned int lc[4];
    int lane = threadIdx.x & 63;
    int wave = threadIdx.x >> 6;
    if (lane == 0) { ls[wave] = sd; ls2[wave] = s2d; lc[wave] = c; }
    __syncthreads();
    if (threadIdx.x == 0) {
        double bs = 0.0, bs2 = 0.0;
        unsigned long long bc = 0;
#pragma unroll
        for (int w = 0; w < 4; ++w) { bs += ls[w]; bs2 += ls2[w]; bc += lc[w]; }
        ws[blockIdx.x]            = bs;
        ws[NBLK + blockIdx.x]     = bs2;
        ws[2 * NBLK + blockIdx.x] = (double)bc;
    }
}

// Fused final-reduce + gather: every block redundantly folds the 2048
// partials (48 KB, L2-resident) then gathers its slice of the output.
__global__ __launch_bounds__(NTHR) void fp_gather(const float* __restrict__ x,
                                                  const double* __restrict__ ws,
                                                  float* __restrict__ out, int T) {
    double s = 0.0, s2 = 0.0, c = 0.0;
    for (int i = threadIdx.x; i < NBLK; i += NTHR) {
        s  += ws[i];
        s2 += ws[NBLK + i];
        c  += ws[2 * NBLK + i];
    }
#pragma unroll
    for (int off = 32; off > 0; off >>= 1) {
        s  += __shfl_down(s, off, 64);
        s2 += __shfl_down(s2, off, 64);
        c  += __shfl_down(c, off, 64);
    }
    __shared__ double ls[4], ls2[4], lc[4];
    __shared__ double sm_mean, sm_inv_std;
    int lane = threadIdx.x & 63;
    int wave = threadIdx.x >> 6;
    if (lane == 0) { ls[wave] = s; ls2[wave] = s2; lc[wave] = c; }
    __syncthreads();
    if (threadIdx.x == 0) {
        double S1 = 0.0, S2 = 0.0, dc = 0.0;
#pragma unroll
        for (int w = 0; w < 4; ++w) { S1 += ls[w]; S2 += ls2[w]; dc += lc[w]; }

        double mean = S1 / dc;
        double m2 = (S1 - dc * mean) / dc;   // fp residual, mirrors ref structure
        double mu = mean + m2;               // var is about (x - mean - m2)
        double var = (S2 - 2.0 * mu * S1 + dc * mu * mu) / (dc - 1.0);
        sm_mean = mean;
        sm_inv_std = 1.0 / sqrt(var);
    }
    __syncthreads();

    int t = blockIdx.x * NTHR + threadIdx.x;
    const int total = FIXED_FRAMES * N_SEL * 3;
    if (t >= total) return;

    double mean = sm_mean;
    double inv_std = sm_inv_std;

    int f = t / (N_SEL * 3);
    int r = t - f * (N_SEL * 3);
    int l = r / 3;
    int ch = r - l * 3;

    // nearest-exact resample index, replicated in float32 like the jax/f32 ref
    float scale = (float)T / 30.0f;
    int fi = (int)floorf(((float)f + 0.5f) * scale);
    if (fi > T - 1) fi = T - 1;
    if (fi < 0) fi = 0;

    float v = x[(size_t)fi * (N_LM * 3) + (size_t)c_sel[l] * 3 + ch];
    out[t] = (v == v) ? (float)(((double)v - mean) * inv_std) : 0.0f;
}

extern "C" void kernel_launch(void* const* d_in, const int* in_sizes, int n_in,
                              void* d_out, int out_size, void* d_ws, size_t ws_size,
                              hipStream_t stream) {
    const float* x = (const float*)d_in[0];
    float* out = (float*)d_out;
    double* ws = (double*)d_ws;

    int n = in_sizes[0];             // 16384*543*3 = 26,689,536 (divisible by 4)
    int n4 = n / 4;
    int T = n / (N_LM * 3);

    fp_reduce<<<NBLK, NTHR, 0, stream>>>((const f32x4*)x, n4, ws);

    const int total = FIXED_FRAMES * N_SEL * 3;  // 9630
    fp_gather<<<(total + NTHR - 1) / NTHR, NTHR, 0, stream>>>(x, ws, out, T);
}